// Round 1
// baseline (132.414 us; speedup 1.0000x reference)
//
#include <hip/hip_runtime.h>
#include <math.h>

// Problem constants (fixed by the reference)
constexpr int NFFT = 256;          // OVERLAPS + STRIDES
constexpr int HOP  = 216;          // STRIDES
constexpr int PAD  = 20;           // M//2 == OVERLAPS/2
constexpr int MT   = 41;           // FIR taps
constexpr int LP   = NFFT + 2 * PAD; // 296

// One block per (batch b, frame s). 256 threads.
// Thread t owns time/freq bin t for both modes outside the FFT stages;
// inside an FFT stage, thread tid does butterfly j = tid&127 of mode tid>>7.
__global__ __launch_bounds__(256)
void eq_pbc_kernel(const float* __restrict__ x_real,
                   const float* __restrict__ x_imag,
                   const float* __restrict__ task_info,
                   const float* __restrict__ h_real,
                   const float* __restrict__ h_imag,
                   float* __restrict__ out,
                   int B, int L, int steps)
{
    __shared__ float Ar[2][2][NFFT];   // [pingpong][mode][idx]
    __shared__ float Ai[2][2][NFFT];
    __shared__ float Wr[NFFT], Wi[NFFT];  // W[k] = exp(-2*pi*i*k/256)
    __shared__ float Iarr[LP];            // circularly padded intensity
    __shared__ float hr[MT], hi[MT];

    const int tid = threadIdx.x;
    const int blk = blockIdx.x;
    const int b   = blk / steps;
    const int s   = blk - b * steps;
    const int l0  = HOP * s;

    // Twiddle table (one sincos per thread, reused by all 16 stages)
    {
        float sv, cv;
        __sincosf(-6.283185307179586f * (1.0f / 256.0f) * (float)tid, &sv, &cv);
        Wr[tid] = cv; Wi[tid] = sv;
    }
    if (tid < MT) { hr[tid] = h_real[tid]; hi[tid] = h_imag[tid]; }

    // Load frame: x[b, l0+t, m], m in {0,1} -> one float2 per component
    {
        const float2 vr = ((const float2*)x_real)[(size_t)b * L + l0 + tid];
        const float2 vi = ((const float2*)x_imag)[(size_t)b * L + l0 + tid];
        Ar[0][0][tid] = vr.x; Ar[0][1][tid] = vr.y;
        Ai[0][0][tid] = vi.x; Ai[0][1][tid] = vi.y;
    }
    __syncthreads();

    const int j  = tid & 127;
    const int md = tid >> 7;

    // Forward FFT-256, Stockham DIF radix-2, autosorted.
    // Stage k: reads buf (k&1), writes buf (k&1)^1; after 8 stages result in buf 0.
    #pragma unroll
    for (int k = 0; k < 8; ++k) {
        const int cur = k & 1, nxt = cur ^ 1;
        const int sN = 1 << k, smask = sN - 1;
        const float ar = Ar[cur][md][j],       ai = Ai[cur][md][j];
        const float br = Ar[cur][md][j + 128], bi = Ai[cur][md][j + 128];
        const int tw = j & ~smask;            // wp = W256[(j>>k)<<k]
        const float wr = Wr[tw], wi = Wi[tw];
        const int w0 = ((j >> k) << (k + 1)) | (j & smask);
        const float dr = ar - br, di = ai - bi;
        Ar[nxt][md][w0] = ar + br;
        Ai[nxt][md][w0] = ai + bi;
        Ar[nxt][md][w0 + sN] = dr * wr - di * wi;
        Ai[nxt][md][w0 + sN] = dr * wi + di * wr;
        __syncthreads();
    }

    // Intensity summed over modes, written with circular padding of 20 each side
    {
        const float v = Ar[0][0][tid] * Ar[0][0][tid] + Ai[0][0][tid] * Ai[0][0][tid]
                      + Ar[0][1][tid] * Ar[0][1][tid] + Ai[0][1][tid] * Ai[0][1][tid];
        Iarr[PAD + tid] = v;
        if (tid < PAD)        Iarr[NFFT + PAD + tid] = v;          // right pad = I[0:20]
        if (tid >= NFFT - PAD) Iarr[tid - (NFFT - PAD)] = v;       // left pad  = I[236:256]
    }
    __syncthreads();

    // phi = 41-tap cross-correlation of padded intensity with (h_real, h_imag);
    // multiplier c = 1 + i*P*phi = (1 - P*phi_i) + i*(P*phi_r)
    const float P = exp2f(task_info[4 * b] * 0.33219280948873623f) * 0.5f; // 10^(ti/10)/Nm
    float cr, ci;
    {
        float pr = 0.f, pi = 0.f;
        #pragma unroll
        for (int t = 0; t < MT; ++t) {
            const float iv = Iarr[tid + t];   // stride-1 across lanes: 2-way, free
            pr = fmaf(iv, hr[t], pr);         // h[t]: broadcast, free
            pi = fmaf(iv, hi[t], pi);
        }
        cr = 1.0f - P * pi;
        ci = P * pr;
    }
    // Modulate in place (thread tid exclusively owns bin tid of buf 0)
    #pragma unroll
    for (int m = 0; m < 2; ++m) {
        const float xr_ = Ar[0][m][tid], xi_ = Ai[0][m][tid];
        Ar[0][m][tid] = xr_ * cr - xi_ * ci;
        Ai[0][m][tid] = xr_ * ci + xi_ * cr;
    }
    __syncthreads();

    // Inverse FFT: identical structure, conjugated twiddles; 1/256 folded into store
    #pragma unroll
    for (int k = 0; k < 8; ++k) {
        const int cur = k & 1, nxt = cur ^ 1;
        const int sN = 1 << k, smask = sN - 1;
        const float ar = Ar[cur][md][j],       ai = Ai[cur][md][j];
        const float br = Ar[cur][md][j + 128], bi = Ai[cur][md][j + 128];
        const int tw = j & ~smask;
        const float wr = Wr[tw], wi = -Wi[tw];
        const int w0 = ((j >> k) << (k + 1)) | (j & smask);
        const float dr = ar - br, di = ai - bi;
        Ar[nxt][md][w0] = ar + br;
        Ai[nxt][md][w0] = ai + bi;
        Ar[nxt][md][w0 + sN] = dr * wr - di * wi;
        Ai[nxt][md][w0 + sN] = dr * wi + di * wr;
        __syncthreads();
    }

    // Overlap-add + wsum normalization + crop, direct to output.
    // Sample l is double-covered iff it lies in an inter-frame overlap region.
    const int l = l0 + tid;
    if (l >= PAD && l < L - PAD) {
        const bool ov = (tid < (NFFT - HOP) && s > 0) || (tid >= HOP && s < steps - 1);
        const float wsc = (ov ? 0.5f : 1.0f) * (1.0f / 256.0f);
        float4 v;
        v.x = Ar[0][0][tid] * wsc;   // out layout: [b][l-20][mode][re/im]
        v.y = Ai[0][0][tid] * wsc;
        v.z = Ar[0][1][tid] * wsc;
        v.w = Ai[0][1][tid] * wsc;
        float* p = out + ((size_t)b * (L - 2 * PAD) + (l - PAD)) * 4;
        if (ov) {
            atomicAdd(p + 0, v.x); atomicAdd(p + 1, v.y);
            atomicAdd(p + 2, v.z); atomicAdd(p + 3, v.w);
        } else {
            *(float4*)p = v;         // exclusive writer: coalesced 16B store
        }
    }
}

extern "C" void kernel_launch(void* const* d_in, const int* in_sizes, int n_in,
                              void* d_out, int out_size, void* d_ws, size_t ws_size,
                              hipStream_t stream) {
    const float* x_real    = (const float*)d_in[0];
    const float* x_imag    = (const float*)d_in[1];
    const float* task_info = (const float*)d_in[2];
    const float* h_real    = (const float*)d_in[3];
    const float* h_imag    = (const float*)d_in[4];

    const int B     = in_sizes[2] / 4;                 // task_info is (B,4)
    const int L     = in_sizes[0] / (B * 2);           // x_real is (B,L,2)
    const int steps = (L - NFFT) / HOP + 1;

    // Output is accumulated into (OLA) — zero it first. Async memset is
    // graph-capture-legal.
    hipMemsetAsync(d_out, 0, (size_t)out_size * sizeof(float), stream);

    eq_pbc_kernel<<<B * steps, 256, 0, stream>>>(
        x_real, x_imag, task_info, h_real, h_imag, (float*)d_out, B, L, steps);
}